// Round 3
// baseline (143.718 us; speedup 1.0000x reference)
//
#include <hip/hip_runtime.h>

// RankNet pairwise loss, N=8192 fp32. Round 3.
// Structure: each thread owns 4 consecutive j (float4 load); each block owns a
// 16-row i-slab whose 32 scalars are loaded UP FRONT into SGPRs (one lgkm wait
// per block), then a fully-unrolled 64-pair pure-register body (4 independent
// chains/lane). Packed triangular 1D grid (2304 equal-work blocks for n=8192).
// Masking via z=-inf (exp2(-inf)=0, log2(1)=0, max(-inf,0)=0 -> contributes 0);
// pair counting on the SALU via ballot+popcount. Fused last-block finalize.

#define TJ 1024            // j-span per block (256 threads x 4 j)
#define TI 16              // i-rows per block
#define RATIO (TJ / TI)    // 64
#define NT 256
#define LOG2E 1.44269504088896340736f
#define LN2   0.69314718055994530942f

__device__ __forceinline__ void pair_op(float ti, float pi, float tjv, float pjv,
                                        bool extra_ok, float neg_inf,
                                        float& sumH, float& sumW, unsigned int& cnt)
{
    const float td = ti - tjv;
    const float pd = pi - pjv;
    float z = (td > 0.f) ? -pd : pd;          // -sign(td)*pd
    const bool valid = (td != 0.f) & extra_ok;
    z = valid ? z : neg_inf;                  // invalid -> contributes exactly 0
    cnt += (unsigned int)__popcll(__ballot(valid));   // SALU: s_bcnt1 + s_add
    const float e = __builtin_amdgcn_exp2f(-LOG2E * __builtin_fabsf(z));
    sumW += __builtin_amdgcn_logf(1.f + e);   // log2(1+e)
    sumH += __builtin_fmaxf(z, 0.f);
}

__global__ __launch_bounds__(NT, 8) void rank_pairs_kernel(
    const float* __restrict__ pred, const float* __restrict__ target, int n,
    float* __restrict__ part_sum, unsigned int* __restrict__ part_cnt,
    unsigned int* __restrict__ done_cnt, int nblocks, float* __restrict__ out)
{
    int bx, iy, bid;
    if (gridDim.y == 1) {
        // packed triangle: cum(bx) = RATIO*bx*(bx+1)/2 = 32*bx*(bx+1)
        bid = (int)blockIdx.x;
        bx = (int)__builtin_sqrtf((float)bid * (2.0f / (float)RATIO));
        while ((RATIO / 2) * (bx + 1) * (bx + 2) <= bid) ++bx;
        while ((RATIO / 2) * bx * (bx + 1) > bid) --bx;
        iy = bid - (RATIO / 2) * bx * (bx + 1);
    } else {
        bx = (int)blockIdx.x; iy = (int)blockIdx.y;
        bid = iy * (int)gridDim.x + bx;
    }

    const int j_base = bx * TJ;
    const int i_base = iy * TI;
    const int j0     = j_base + (int)threadIdx.x * 4;

    float sumH = 0.f, sumW = 0.f;
    unsigned int cnt = 0u;                 // wave-uniform (ballot-counted)
    const float neg_inf = -__builtin_inff();

    if (gridDim.y == 1) {
        // ---- fast path: n % TJ == 0, every tile fully in-bounds ----
        const float4 p4 = *(const float4*)(pred + j0);
        const float4 t4 = *(const float4*)(target + j0);
        const float pjv[4] = {p4.x, p4.y, p4.z, p4.w};
        const float tjv[4] = {t4.x, t4.y, t4.z, t4.w};

        // hoist the whole i-slab into SGPRs (uniform addresses -> s_load)
        float ts[TI], ps[TI];
        #pragma unroll
        for (int k = 0; k < TI; ++k) {
            ts[k] = target[i_base + k];
            ps[k] = pred[i_base + k];
        }

        if (i_base + TI <= j_base) {
            // strictly above diagonal: i < j guaranteed
            #pragma unroll
            for (int k = 0; k < TI; ++k)
                #pragma unroll
                for (int jj = 0; jj < 4; ++jj)
                    pair_op(ts[k], ps[k], tjv[jj], pjv[jj], true, neg_inf,
                            sumH, sumW, cnt);
        } else {
            // diagonal-straddling tile: per-pair i<j check
            #pragma unroll
            for (int k = 0; k < TI; ++k)
                #pragma unroll
                for (int jj = 0; jj < 4; ++jj)
                    pair_op(ts[k], ps[k], tjv[jj], pjv[jj],
                            (i_base + k) < (j0 + jj), neg_inf, sumH, sumW, cnt);
        }
    } else {
        // ---- generic path (n not a multiple of TJ): full masking ----
        if (i_base < j_base + TJ && i_base < n) {
            for (int k = 0; k < TI; ++k) {
                const int i = i_base + k;
                if (i >= n) break;
                const float ti = target[i];
                const float pi = pred[i];
                for (int jj = 0; jj < 4; ++jj) {
                    const int  j   = j0 + jj;
                    const bool jin = (j < n);
                    const int  jc  = jin ? j : (n - 1);
                    pair_op(ti, pi, target[jc], pred[jc],
                            jin && (i < j), neg_inf, sumH, sumW, cnt);
                }
            }
        }
    }

    float sum = sumH + LN2 * sumW;         // softplus recombine (beta = 1)

    // wave(64) shuffle reduce for sum; cnt is already wave-uniform
    #pragma unroll
    for (int off = 32; off > 0; off >>= 1)
        sum += __shfl_down(sum, off, 64);

    __shared__ float        s_s[NT / 64];
    __shared__ unsigned int s_c[NT / 64];
    __shared__ bool         s_last;
    const int lane = threadIdx.x & 63;
    const int wv   = threadIdx.x >> 6;
    if (lane == 0) { s_s[wv] = sum; s_c[wv] = cnt; }
    __syncthreads();
    if (threadIdx.x == 0) {
        float bs = 0.f; unsigned int bc = 0u;
        #pragma unroll
        for (int w = 0; w < NT / 64; ++w) { bs += s_s[w]; bc += s_c[w]; }
        part_sum[bid] = bs;
        part_cnt[bid] = bc;
        __threadfence();                   // release partials (device scope)
        const unsigned int prev = atomicAdd(done_cnt, 1u);
        s_last = (prev == (unsigned int)(nblocks - 1));
    }
    __syncthreads();

    if (s_last) {
        __threadfence();                   // acquire all partials
        float fs = 0.f; unsigned int fc = 0u;
        for (int idx = (int)threadIdx.x; idx < nblocks; idx += NT) {
            fs += part_sum[idx];
            fc += part_cnt[idx];
        }
        #pragma unroll
        for (int off = 32; off > 0; off >>= 1) {
            fs += __shfl_down(fs, off, 64);
            fc += __shfl_down(fc, off, 64);
        }
        if (lane == 0) { s_s[wv] = fs; s_c[wv] = fc; }
        __syncthreads();
        if (threadIdx.x == 0) {
            float bs = 0.f; unsigned int bc = 0u;
            #pragma unroll
            for (int w = 0; w < NT / 64; ++w) { bs += s_s[w]; bc += s_c[w]; }
            out[0] = (bc > 0u) ? bs / (float)bc : 0.f;
        }
    }
}

extern "C" void kernel_launch(void* const* d_in, const int* in_sizes, int n_in,
                              void* d_out, int out_size, void* d_ws, size_t ws_size,
                              hipStream_t stream)
{
    const float* pred   = (const float*)d_in[0];
    const float* target = (const float*)d_in[1];
    float* out = (float*)d_out;
    const int n = in_sizes[0];

    dim3 grid;
    int nblocks;
    if (n >= TJ && (n % TJ == 0)) {
        const int gx = n / TJ;                         // 8 for n=8192
        nblocks = (RATIO / 2) * gx * (gx + 1);         // 2304 triangle blocks
        grid = dim3((unsigned)nblocks, 1);
    } else {
        const int gx = (n + TJ - 1) / TJ;
        const int gy = (n + TI - 1) / TI;
        nblocks = gx * gy;
        grid = dim3((unsigned)gx, (unsigned)gy);
    }

    float*        part_sum = (float*)d_ws;
    unsigned int* part_cnt = (unsigned int*)((char*)d_ws + (size_t)nblocks * sizeof(float));
    unsigned int* done_cnt = (unsigned int*)((char*)d_ws + (size_t)2 * nblocks * sizeof(float));

    hipMemsetAsync(done_cnt, 0, sizeof(unsigned int), stream);
    rank_pairs_kernel<<<grid, NT, 0, stream>>>(pred, target, n, part_sum, part_cnt,
                                               done_cnt, nblocks, out);
}

// Round 4
// 124.286 us; speedup vs baseline: 1.1563x; 1.1563x over previous
//
#include <hip/hip_runtime.h>

// RankNet pairwise loss, N=8192 fp32. Round 4.
// R3's 71 MB WRITE_SIZE was the ts[]/ps[] slab spilling to scratch
// (launch_bounds min-waves=8 capped VGPRs at 64). Fixes:
//  (1) i-slab forced into SGPRs via v_readfirstlane (wave-uniform broadcast
//      loads) -- SGPRs cannot spill, and frees the VGPR budget;
//  (2) launch_bounds (256,4) -> 128-VGPR cap for the 4 j-chains;
//  (3) product trick: prod *= (1+e) via one fma per pair, ONE v_log_f32 per
//      thread per tile (factors in [1,2], 64 factors <= 2^64, fp32-safe).
// Keeps: packed triangular 1D grid, -inf masking, ballot/SALU pair count,
// fused last-block finalize.

#define TJ 1024            // j-span per block (256 threads x 4 j)
#define TI 16              // i-rows per block
#define RATIO (TJ / TI)    // 64
#define NT 256
#define LOG2E 1.44269504088896340736f
#define LN2   0.69314718055994530942f

__device__ __forceinline__ float rfl(float x) {
    // wave-uniform value -> SGPR (v_readfirstlane_b32)
    return __int_as_float(__builtin_amdgcn_readfirstlane(__float_as_int(x)));
}

__device__ __forceinline__ void pair_op(float ti, float pi, float tjv, float pjv,
                                        bool extra_ok, float neg_inf,
                                        float& prod, float& sumH, unsigned int& cnt)
{
    const float td = ti - tjv;
    const float pd = pi - pjv;
    float z = (td > 0.f) ? -pd : pd;          // -sign(td)*pd  (cmp + cndmask -pd)
    const bool valid = (td != 0.f) & extra_ok;
    z = valid ? z : neg_inf;                  // invalid -> e=0, max(z,0)=0
    cnt += (unsigned int)__popcll(__ballot(valid));   // SALU s_bcnt1+s_add
    const float e = __builtin_amdgcn_exp2f(-LOG2E * __builtin_fabsf(z));
    prod = __builtin_fmaf(prod, e, prod);     // prod *= (1 + e)
    sumH += __builtin_fmaxf(z, 0.f);
}

__global__ __launch_bounds__(NT, 4) void rank_pairs_kernel(
    const float* __restrict__ pred, const float* __restrict__ target, int n,
    float* __restrict__ part_sum, unsigned int* __restrict__ part_cnt,
    unsigned int* __restrict__ done_cnt, int nblocks, float* __restrict__ out)
{
    int bx, iy, bid;
    if (gridDim.y == 1) {
        // packed triangle: cum(bx) = (RATIO/2)*bx*(bx+1)
        bid = (int)blockIdx.x;
        bx = (int)__builtin_sqrtf((float)bid * (2.0f / (float)RATIO));
        while ((RATIO / 2) * (bx + 1) * (bx + 2) <= bid) ++bx;
        while ((RATIO / 2) * bx * (bx + 1) > bid) --bx;
        iy = bid - (RATIO / 2) * bx * (bx + 1);
    } else {
        bx = (int)blockIdx.x; iy = (int)blockIdx.y;
        bid = iy * (int)gridDim.x + bx;
    }

    const int j_base = bx * TJ;
    const int i_base = iy * TI;
    const int j0     = j_base + (int)threadIdx.x * 4;

    float prod[4] = {1.f, 1.f, 1.f, 1.f};
    float sumH[4] = {0.f, 0.f, 0.f, 0.f};
    unsigned int cnt = 0u;                 // wave-uniform (ballot-counted)
    const float neg_inf = -__builtin_inff();
    float sum = 0.f;

    if (gridDim.y == 1) {
        // ---- fast path: n % TJ == 0, every tile fully in-bounds ----
        const float4 p4 = *(const float4*)(pred + j0);
        const float4 t4 = *(const float4*)(target + j0);
        const float pjv[4] = {p4.x, p4.y, p4.z, p4.w};
        const float tjv[4] = {t4.x, t4.y, t4.z, t4.w};

        // i-slab: broadcast vector loads, then force into SGPRs
        float ts[TI], ps[TI];
        #pragma unroll
        for (int k4 = 0; k4 < TI / 4; ++k4) {
            const float4 ti4 = *(const float4*)(target + i_base + 4 * k4);
            const float4 pi4 = *(const float4*)(pred   + i_base + 4 * k4);
            ts[4*k4+0] = rfl(ti4.x); ts[4*k4+1] = rfl(ti4.y);
            ts[4*k4+2] = rfl(ti4.z); ts[4*k4+3] = rfl(ti4.w);
            ps[4*k4+0] = rfl(pi4.x); ps[4*k4+1] = rfl(pi4.y);
            ps[4*k4+2] = rfl(pi4.z); ps[4*k4+3] = rfl(pi4.w);
        }

        if (i_base + TI <= j_base) {
            // strictly above diagonal: i < j guaranteed
            #pragma unroll
            for (int k = 0; k < TI; ++k)
                #pragma unroll
                for (int jj = 0; jj < 4; ++jj)
                    pair_op(ts[k], ps[k], tjv[jj], pjv[jj], true, neg_inf,
                            prod[jj], sumH[jj], cnt);
        } else {
            // diagonal-straddling tile: per-pair i<j check
            #pragma unroll
            for (int k = 0; k < TI; ++k)
                #pragma unroll
                for (int jj = 0; jj < 4; ++jj)
                    pair_op(ts[k], ps[k], tjv[jj], pjv[jj],
                            (i_base + k) < (j0 + jj), neg_inf,
                            prod[jj], sumH[jj], cnt);
        }
        const float sumW = __builtin_amdgcn_logf(((prod[0] * prod[1]) *
                                                  (prod[2] * prod[3])));
        sum = ((sumH[0] + sumH[1]) + (sumH[2] + sumH[3])) + LN2 * sumW;
    } else {
        // ---- generic path (n not a multiple of TJ): full masking ----
        if (i_base < j_base + TJ && i_base < n) {
            for (int k = 0; k < TI; ++k) {
                const int i = i_base + k;
                if (i >= n) break;
                const float ti = target[i];
                const float pi = pred[i];
                for (int jj = 0; jj < 4; ++jj) {
                    const int  j   = j0 + jj;
                    const bool jin = (j < n);
                    const int  jc  = jin ? j : (n - 1);
                    pair_op(ti, pi, target[jc], pred[jc],
                            jin && (i < j), neg_inf, prod[jj], sumH[jj], cnt);
                }
            }
        }
        const float sumW = __builtin_amdgcn_logf(((prod[0] * prod[1]) *
                                                  (prod[2] * prod[3])));
        sum = ((sumH[0] + sumH[1]) + (sumH[2] + sumH[3])) + LN2 * sumW;
    }

    // wave(64) shuffle reduce for sum; cnt is already wave-uniform
    #pragma unroll
    for (int off = 32; off > 0; off >>= 1)
        sum += __shfl_down(sum, off, 64);

    __shared__ float        s_s[NT / 64];
    __shared__ unsigned int s_c[NT / 64];
    __shared__ bool         s_last;
    const int lane = threadIdx.x & 63;
    const int wv   = threadIdx.x >> 6;
    if (lane == 0) { s_s[wv] = sum; s_c[wv] = cnt; }
    __syncthreads();
    if (threadIdx.x == 0) {
        float bs = 0.f; unsigned int bc = 0u;
        #pragma unroll
        for (int w = 0; w < NT / 64; ++w) { bs += s_s[w]; bc += s_c[w]; }
        part_sum[bid] = bs;
        part_cnt[bid] = bc;
        __threadfence();                   // release partials (device scope)
        const unsigned int prev = atomicAdd(done_cnt, 1u);
        s_last = (prev == (unsigned int)(nblocks - 1));
    }
    __syncthreads();

    if (s_last) {
        __threadfence();                   // acquire all partials
        float fs = 0.f; unsigned int fc = 0u;
        for (int idx = (int)threadIdx.x; idx < nblocks; idx += NT) {
            fs += part_sum[idx];
            fc += part_cnt[idx];
        }
        #pragma unroll
        for (int off = 32; off > 0; off >>= 1) {
            fs += __shfl_down(fs, off, 64);
            fc += __shfl_down(fc, off, 64);
        }
        if (lane == 0) { s_s[wv] = fs; s_c[wv] = fc; }
        __syncthreads();
        if (threadIdx.x == 0) {
            float bs = 0.f; unsigned int bc = 0u;
            #pragma unroll
            for (int w = 0; w < NT / 64; ++w) { bs += s_s[w]; bc += s_c[w]; }
            out[0] = (bc > 0u) ? bs / (float)bc : 0.f;
        }
    }
}

extern "C" void kernel_launch(void* const* d_in, const int* in_sizes, int n_in,
                              void* d_out, int out_size, void* d_ws, size_t ws_size,
                              hipStream_t stream)
{
    const float* pred   = (const float*)d_in[0];
    const float* target = (const float*)d_in[1];
    float* out = (float*)d_out;
    const int n = in_sizes[0];

    dim3 grid;
    int nblocks;
    if (n >= TJ && (n % TJ == 0)) {
        const int gx = n / TJ;                         // 8 for n=8192
        nblocks = (RATIO / 2) * gx * (gx + 1);         // 2304 triangle blocks
        grid = dim3((unsigned)nblocks, 1);
    } else {
        const int gx = (n + TJ - 1) / TJ;
        const int gy = (n + TI - 1) / TI;
        nblocks = gx * gy;
        grid = dim3((unsigned)gx, (unsigned)gy);
    }

    float*        part_sum = (float*)d_ws;
    unsigned int* part_cnt = (unsigned int*)((char*)d_ws + (size_t)nblocks * sizeof(float));
    unsigned int* done_cnt = (unsigned int*)((char*)d_ws + (size_t)2 * nblocks * sizeof(float));

    hipMemsetAsync(done_cnt, 0, sizeof(unsigned int), stream);
    rank_pairs_kernel<<<grid, NT, 0, stream>>>(pred, target, n, part_sum, part_cnt,
                                               done_cnt, nblocks, out);
}

// Round 5
// 83.862 us; speedup vs baseline: 1.7137x; 1.4820x over previous
//
#include <hip/hip_runtime.h>

// RankNet pairwise loss, N=8192 fp32. Round 5.
// R3/R4 lesson: holding the 32-float i-slab in the register file (VGPR arrays
// or readfirstlane->SGPR) loses the allocator fight and spills to scratch
// (71 MB / 18.6 MB WRITE_SIZE). Fix: stage the slab in LDS (256 B) and read
// it with broadcast ds_read_b64 (one per i-row, shared by 4 pair-ops).
// Live VGPRs ~30 -> no spill; __launch_bounds__(256,8) for 8 waves/SIMD.
// Keeps: 4 j-chains per thread (float4), product trick (one v_log per 2
// chains; 32 factors<=2^32/chain, pairwise-combined <=2^64 < FLT_MAX),
// ballot/SALU pair count, packed triangular 1D grid, fused finalize.

#define TJ 1024            // j-span per block (256 threads x 4 j)
#define TI 32              // i-rows per block
#define RATIO (TJ / TI)    // 32
#define NT 256
#define LOG2E 1.44269504088896340736f
#define LN2   0.69314718055994530942f

__device__ __forceinline__ void pair_op(float ti, float pi, float tjv, float pjv,
                                        bool iok, float neg_inf,
                                        float& prod, float& sumH, unsigned int& cnt)
{
    const float td = ti - tjv;
    const float pd = pi - pjv;
    float z = (td > 0.f) ? -pd : pd;          // -sign(td)*pd (cndmask w/ neg mod)
    const bool valid = (td != 0.f) & iok;
    z = valid ? z : neg_inf;                  // invalid -> e=0, max(z,0)=0
    cnt += (unsigned int)__popcll(__ballot(valid));   // SALU s_bcnt1+s_add
    const float e = __builtin_amdgcn_exp2f(-LOG2E * __builtin_fabsf(z));
    prod = __builtin_fmaf(prod, e, prod);     // prod *= (1 + e)
    sumH += __builtin_fmaxf(z, 0.f);
}

__global__ __launch_bounds__(NT, 8) void rank_pairs_kernel(
    const float* __restrict__ pred, const float* __restrict__ target, int n,
    float* __restrict__ part_sum, unsigned int* __restrict__ part_cnt,
    unsigned int* __restrict__ done_cnt, int nblocks, float* __restrict__ out)
{
    int bx, iy, bid;
    if (gridDim.y == 1) {
        // packed triangle: cum(bx) = (RATIO/2)*bx*(bx+1)
        bid = (int)blockIdx.x;
        bx = (int)__builtin_sqrtf((float)bid * (2.0f / (float)RATIO));
        while ((RATIO / 2) * (bx + 1) * (bx + 2) <= bid) ++bx;
        while ((RATIO / 2) * bx * (bx + 1) > bid) --bx;
        iy = bid - (RATIO / 2) * bx * (bx + 1);
    } else {
        bx = (int)blockIdx.x; iy = (int)blockIdx.y;
        bid = iy * (int)gridDim.x + bx;
    }

    const int j_base = bx * TJ;
    const int i_base = iy * TI;
    const int j0     = j_base + (int)threadIdx.x * 4;

    __shared__ float2 s_tp[TI];               // 256 B i-slab stage

    float prod[4] = {1.f, 1.f, 1.f, 1.f};
    float sumH[4] = {0.f, 0.f, 0.f, 0.f};
    unsigned int cnt = 0u;                    // wave-uniform (ballot-counted)
    const float neg_inf = -__builtin_inff();
    float sum = 0.f;

    if (gridDim.y == 1) {
        // ---- fast path: n % TJ == 0, every tile fully in-bounds ----
        if (threadIdx.x < TI) {
            const int i = i_base + (int)threadIdx.x;
            s_tp[threadIdx.x] = make_float2(target[i], pred[i]);
        }
        __syncthreads();

        const float4 p4 = *(const float4*)(pred + j0);
        const float4 t4 = *(const float4*)(target + j0);
        const float pjv[4] = {p4.x, p4.y, p4.z, p4.w};
        const float tjv[4] = {t4.x, t4.y, t4.z, t4.w};

        if (i_base + TI <= j_base) {
            // strictly above diagonal: i < j guaranteed
            #pragma unroll 8
            for (int k = 0; k < TI; ++k) {
                const float2 tp = s_tp[k];    // broadcast ds_read_b64
                #pragma unroll
                for (int jj = 0; jj < 4; ++jj)
                    pair_op(tp.x, tp.y, tjv[jj], pjv[jj], true, neg_inf,
                            prod[jj], sumH[jj], cnt);
            }
        } else {
            // diagonal-straddling tile: per-pair i<j check
            #pragma unroll 8
            for (int k = 0; k < TI; ++k) {
                const float2 tp = s_tp[k];
                #pragma unroll
                for (int jj = 0; jj < 4; ++jj)
                    pair_op(tp.x, tp.y, tjv[jj], pjv[jj],
                            (i_base + k) < (j0 + jj), neg_inf,
                            prod[jj], sumH[jj], cnt);
            }
        }
    } else {
        // ---- generic path (n not a multiple of TJ): full masking ----
        if (i_base < j_base + TJ && i_base < n) {
            for (int k = 0; k < TI; ++k) {
                const int i = i_base + k;
                if (i >= n) break;
                const float ti = target[i];
                const float pi = pred[i];
                for (int jj = 0; jj < 4; ++jj) {
                    const int  j   = j0 + jj;
                    const bool jin = (j < n);
                    const int  jc  = jin ? j : (n - 1);
                    pair_op(ti, pi, target[jc], pred[jc],
                            jin && (i < j), neg_inf, prod[jj], sumH[jj], cnt);
                }
            }
        }
    }

    // combine chains pairwise (<=2^64, fp32-safe), two logs total
    const float sumW = __builtin_amdgcn_logf(prod[0] * prod[1]) +
                       __builtin_amdgcn_logf(prod[2] * prod[3]);
    sum = ((sumH[0] + sumH[1]) + (sumH[2] + sumH[3])) + LN2 * sumW;

    // wave(64) shuffle reduce for sum; cnt is already wave-uniform
    #pragma unroll
    for (int off = 32; off > 0; off >>= 1)
        sum += __shfl_down(sum, off, 64);

    __shared__ float        s_s[NT / 64];
    __shared__ unsigned int s_c[NT / 64];
    __shared__ bool         s_last;
    const int lane = threadIdx.x & 63;
    const int wv   = threadIdx.x >> 6;
    if (lane == 0) { s_s[wv] = sum; s_c[wv] = cnt; }
    __syncthreads();
    if (threadIdx.x == 0) {
        float bs = 0.f; unsigned int bc = 0u;
        #pragma unroll
        for (int w = 0; w < NT / 64; ++w) { bs += s_s[w]; bc += s_c[w]; }
        part_sum[bid] = bs;
        part_cnt[bid] = bc;
        __threadfence();                   // release partials (device scope)
        const unsigned int prev = atomicAdd(done_cnt, 1u);
        s_last = (prev == (unsigned int)(nblocks - 1));
    }
    __syncthreads();

    if (s_last) {
        __threadfence();                   // acquire all partials
        float fs = 0.f; unsigned int fc = 0u;
        for (int idx = (int)threadIdx.x; idx < nblocks; idx += NT) {
            fs += part_sum[idx];
            fc += part_cnt[idx];
        }
        #pragma unroll
        for (int off = 32; off > 0; off >>= 1) {
            fs += __shfl_down(fs, off, 64);
            fc += __shfl_down(fc, off, 64);
        }
        if (lane == 0) { s_s[wv] = fs; s_c[wv] = fc; }
        __syncthreads();
        if (threadIdx.x == 0) {
            float bs = 0.f; unsigned int bc = 0u;
            #pragma unroll
            for (int w = 0; w < NT / 64; ++w) { bs += s_s[w]; bc += s_c[w]; }
            out[0] = (bc > 0u) ? bs / (float)bc : 0.f;
        }
    }
}

extern "C" void kernel_launch(void* const* d_in, const int* in_sizes, int n_in,
                              void* d_out, int out_size, void* d_ws, size_t ws_size,
                              hipStream_t stream)
{
    const float* pred   = (const float*)d_in[0];
    const float* target = (const float*)d_in[1];
    float* out = (float*)d_out;
    const int n = in_sizes[0];

    dim3 grid;
    int nblocks;
    if (n >= TJ && (n % TJ == 0)) {
        const int gx = n / TJ;                         // 8 for n=8192
        nblocks = (RATIO / 2) * gx * (gx + 1);         // 1152 triangle blocks
        grid = dim3((unsigned)nblocks, 1);
    } else {
        const int gx = (n + TJ - 1) / TJ;
        const int gy = (n + TI - 1) / TI;
        nblocks = gx * gy;
        grid = dim3((unsigned)gx, (unsigned)gy);
    }

    float*        part_sum = (float*)d_ws;
    unsigned int* part_cnt = (unsigned int*)((char*)d_ws + (size_t)nblocks * sizeof(float));
    unsigned int* done_cnt = (unsigned int*)((char*)d_ws + (size_t)2 * nblocks * sizeof(float));

    hipMemsetAsync(done_cnt, 0, sizeof(unsigned int), stream);
    rank_pairs_kernel<<<grid, NT, 0, stream>>>(pred, target, n, part_sum, part_cnt,
                                               done_cnt, nblocks, out);
}